// Round 9
// baseline (663.623 us; speedup 1.0000x reference)
//
#include <hip/hip_runtime.h>
#include <hip/hip_bf16.h>
#include <math.h>

#define Hd   512
#define FPd  256
#define Ed   512
#define NFd  768
#define Ld   512
#define Bd   32
#define K2H  1024            // 2H
#define Nd   1024            // NF + FP
#define Md   (Ld * Bd)       // 16384

typedef _Float16 f16x8  __attribute__((ext_vector_type(8)));
typedef float    f32x4  __attribute__((ext_vector_type(4)));
typedef float    f32x16 __attribute__((ext_vector_type(16)));

// ---------------------------------------------------------------------------
// Kernel 1: fused W_big build + fp16 hi/lo frag repack (no fp32 round-trip).
//   W_big[n][k] = sum_e F[n][e]*W_feat[e][k]   (n < NF)
//              =  sum_h v[n-NF][h]*W_lin[h][k] (n >= NF)
// grid (kx=8, ny=32), 256 thr. Block: ntile=ny (32 n) x 128 k.
// Phase 1: fp32 compute into regs (16 n per thread).
// Phase 2: via LDS tile, emit MFMA B-frags: Bh/Bl[((ntile*64+ks)*64+lane)*8],
//          n = ntile*32+(lane&31), k = ks*16+(lane>>5)*8+j.
// ---------------------------------------------------------------------------
__global__ __launch_bounds__(256)
void build_wpack(const float* __restrict__ F,
                 const float* __restrict__ Wf,
                 const float* __restrict__ V,
                 const float* __restrict__ Wl,
                 _Float16* __restrict__ Bh, _Float16* __restrict__ Bl) {
    __shared__ float fs[32][64];
    __shared__ float wtile[32][132];    // padded stride
    const int tid = threadIdx.x;
    const int kx  = blockIdx.x;
    const int ny  = blockIdx.y;
    const int n0  = ny * 32;
    const int kl  = tid & 127;          // local k
    const int k   = kx * 128 + kl;
    const int ty  = tid >> 7;

    const float* src;  const float* wsrc;
    if (n0 < NFd) { src = F + (size_t)n0 * Ed;          wsrc = Wf; }
    else          { src = V + (size_t)(n0 - NFd) * Hd;  wsrc = Wl; }

    float acc[16];
#pragma unroll
    for (int i = 0; i < 16; i++) acc[i] = 0.f;

    for (int e0 = 0; e0 < 512; e0 += 64) {
#pragma unroll
        for (int rep = 0; rep < 2; rep++) {
            int idx = rep * 256 + tid;
            int i   = idx >> 4;
            int kq  = idx & 15;
            float4 v4 = *(const float4*)(src + (size_t)i * 512 + e0 + kq * 4);
            *(float4*)(&fs[i][kq * 4]) = v4;
        }
        __syncthreads();
#pragma unroll 4
        for (int kk = 0; kk < 64; kk += 4) {
            float w0 = wsrc[(size_t)(e0 + kk + 0) * K2H + k];
            float w1 = wsrc[(size_t)(e0 + kk + 1) * K2H + k];
            float w2 = wsrc[(size_t)(e0 + kk + 2) * K2H + k];
            float w3 = wsrc[(size_t)(e0 + kk + 3) * K2H + k];
#pragma unroll
            for (int i = 0; i < 16; i++) {
                float4 f4 = *(const float4*)(&fs[ty * 16 + i][kk]);
                acc[i] += f4.x * w0 + f4.y * w1 + f4.z * w2 + f4.w * w3;
            }
        }
        __syncthreads();
    }
    // phase 2: stage to LDS, emit frags
#pragma unroll
    for (int i = 0; i < 16; i++) wtile[ty * 16 + i][kl] = acc[i];
    __syncthreads();
#pragma unroll
    for (int s = 0; s < 2; s++) {
        const int slot = s * 256 + tid;       // 0..511
        const int lane = slot & 63;
        const int ksl  = slot >> 6;           // 0..7
        const int nl   = lane & 31;
        const int kf   = ksl * 16 + (lane >> 5) * 8;
        float w[8];
        *(float4*)(w)     = *(const float4*)(&wtile[nl][kf]);
        *(float4*)(w + 4) = *(const float4*)(&wtile[nl][kf + 4]);
        f16x8 h, l;
#pragma unroll
        for (int j = 0; j < 8; j++) {
            _Float16 hh = (_Float16)w[j];
            h[j] = hh;
            l[j] = (_Float16)(w[j] - (float)hh);
        }
        const size_t fo = ((size_t)((ny * 8 + kx) * 8 + ksl) * 64 + lane) * 8;
        *(f16x8*)(Bh + fo) = h;
        *(f16x8*)(Bl + fo) = l;
    }
}

// ---------------------------------------------------------------------------
// Kernel 1b: bias_big[n]
// ---------------------------------------------------------------------------
__global__ __launch_bounds__(64)
void build_bias(const float* __restrict__ F, const float* __restrict__ bf,
                const float* __restrict__ V, const float* __restrict__ bl,
                float* __restrict__ bias) {
    const int n    = blockIdx.x;
    const int lane = threadIdx.x;
    const float* row; const float* bsrc;
    if (n < NFd) { row = F + (size_t)n * Ed;          bsrc = bf; }
    else         { row = V + (size_t)(n - NFd) * Hd;  bsrc = bl; }
    float a = 0.f;
#pragma unroll
    for (int rep = 0; rep < 8; rep++) {
        int e = rep * 64 + lane;
        a += row[e] * bsrc[e];
    }
#pragma unroll
    for (int off = 1; off < 64; off <<= 1) a += __shfl_xor(a, off);
    if (lane == 0) bias[n] = a;
}

// ---------------------------------------------------------------------------
// Kernel 2: MFMA GEMM (fp16x3 split) + fused softmax + direct transposed
// store to out[b][n][l].
// Grid 256 = (b, lc): block = fixed batch b, 64 consecutive l (64 m-rows).
// 256 thr = 4 WAVES (1 wave/SIMD, launch_bounds(256,1) -> 512-reg budget:
// 256 AGPR acc[2][8] + ~200 VGPR headroom for B-load pipelining).
// Wave wn owns cols wn*256 (8 nt of 32) x 64 rows (2 ms of 32).
// A: BK=128 chunks, LDS f16 hi/lo planes (converted once at stage time),
// double-buffered, XOR-swizzled; enc loads NONTEMPORAL (read-once stream,
// don't evict B from L2). B: direct global frag loads, L2-resident (4 MB).
// Bias pre-folded into acc init.
// ---------------------------------------------------------------------------
__global__ __launch_bounds__(256, 1)
void gemm_direct(const float* __restrict__ enc,
                 const _Float16* __restrict__ Bh,
                 const _Float16* __restrict__ Bl,
                 const float* __restrict__ bias,
                 float* __restrict__ out) {
    // 2 bufs x (hi plane 16KB | lo plane 16KB)
    __shared__ char AsB[2][32768];
    __shared__ float red[4][64];
    __shared__ float redc[64];

    const int tid  = threadIdx.x;
    const int lane = tid & 63;
    const int wn   = tid >> 6;         // wave 0..3 -> 256-col block
    const int hf   = lane >> 5;
    const int l31  = lane & 31;
    const int b    = blockIdx.x >> 3;  // 0..31
    const int l0   = (blockIdx.x & 7) * 64;

    // bias folded into accumulator init
    float bv[8];
#pragma unroll
    for (int nt = 0; nt < 8; nt++) bv[nt] = bias[wn * 256 + nt * 32 + l31];
    f32x16 acc[2][8];
#pragma unroll
    for (int ms = 0; ms < 2; ms++)
#pragma unroll
        for (int nt = 0; nt < 8; nt++)
#pragma unroll
            for (int r = 0; r < 16; r++) acc[ms][nt][r] = bv[nt];

    // staging map: thread -> (row = tid>>2 in 0..63, 32 k at (tid&3)*32)
    const int srow = tid >> 2;
    const int skf  = (tid & 3) * 32;                   // k float offset
    const float* gA = enc + ((size_t)(l0 + srow) * Bd + b) * K2H + skf;
    const uint32_t wswz = (uint32_t)((srow & 15) << 4);
    const uint32_t wb0  = (uint32_t)(srow * 256 + skf * 2);   // byte offset

    // read map: row = ms*32 + l31 -> row&15 == l31&15
    const uint32_t rswz = (uint32_t)((l31 & 15) << 4);

#define STAGE_CHUNK(dst, pf)                                              \
    {                                                                     \
        char* base_ = (dst);                                              \
        _Pragma("unroll")                                                 \
        for (int g = 0; g < 4; g++) {                                     \
            f16x8 h_, l_;                                                 \
            _Pragma("unroll")                                             \
            for (int j = 0; j < 8; j++) {                                 \
                float f_ = (pf)[g * 8 + j];                               \
                _Float16 hh_ = (_Float16)f_;                              \
                h_[j] = hh_;                                              \
                l_[j] = (_Float16)(f_ - (float)hh_);                      \
            }                                                             \
            const uint32_t o_ = (uint32_t)(wb0 + g * 16) ^ wswz;          \
            *(f16x8*)(base_ + o_)         = h_;                           \
            *(f16x8*)(base_ + 16384 + o_) = l_;                           \
        }                                                                 \
    }

    // prologue: stage chunk 0 into buf 0
    {
        float pf[32];
#pragma unroll
        for (int j = 0; j < 8; j++) {
            f32x4 v = __builtin_nontemporal_load((const f32x4*)(gA + 4 * j));
            pf[4 * j + 0] = v.x; pf[4 * j + 1] = v.y;
            pf[4 * j + 2] = v.z; pf[4 * j + 3] = v.w;
        }
        STAGE_CHUNK(AsB[0], pf)
    }

    for (int c = 0; c < 8; ++c) {
        __syncthreads();               // buf[c&1] staged; buf[(c+1)&1] free
        float pf[32];
        if (c < 7) {                   // issue prefetch NOW: flies under MFMA
            const float* g = gA + (c + 1) * 128;
#pragma unroll
            for (int j = 0; j < 8; j++) {
                f32x4 v = __builtin_nontemporal_load((const f32x4*)(g + 4 * j));
                pf[4 * j + 0] = v.x; pf[4 * j + 1] = v.y;
                pf[4 * j + 2] = v.z; pf[4 * j + 3] = v.w;
            }
        }
        const char* hbase = AsB[c & 1];
        const char* lbase = AsB[c & 1] + 16384;
#pragma unroll
        for (int kk = 0; kk < 8; ++kk) {
            const uint32_t ko = (uint32_t)((kk * 32 + hf * 16) ^ rswz);
            f16x8 a_h[2], a_l[2];
#pragma unroll
            for (int ms = 0; ms < 2; ms++) {
                const uint32_t ro = (uint32_t)((ms * 32 + l31) * 256);
                a_h[ms] = *(const f16x8*)(hbase + ro + ko);
                a_l[ms] = *(const f16x8*)(lbase + ro + ko);
            }
#pragma unroll
            for (int nt = 0; nt < 8; ++nt) {
                const size_t fo = ((size_t)((wn * 8 + nt) * 64 + c * 8 + kk) * 64 + lane) * 8;
                f16x8 b_h = *(const f16x8*)(Bh + fo);
                f16x8 b_l = *(const f16x8*)(Bl + fo);
                acc[0][nt] = __builtin_amdgcn_mfma_f32_32x32x16_f16(a_h[0], b_h, acc[0][nt], 0, 0, 0);
                acc[1][nt] = __builtin_amdgcn_mfma_f32_32x32x16_f16(a_h[1], b_h, acc[1][nt], 0, 0, 0);
                acc[0][nt] = __builtin_amdgcn_mfma_f32_32x32x16_f16(a_l[0], b_h, acc[0][nt], 0, 0, 0);
                acc[1][nt] = __builtin_amdgcn_mfma_f32_32x32x16_f16(a_l[1], b_h, acc[1][nt], 0, 0, 0);
                acc[0][nt] = __builtin_amdgcn_mfma_f32_32x32x16_f16(a_h[0], b_l, acc[0][nt], 0, 0, 0);
                acc[1][nt] = __builtin_amdgcn_mfma_f32_32x32x16_f16(a_h[1], b_l, acc[1][nt], 0, 0, 0);
            }
        }
        if (c < 7) STAGE_CHUNK(AsB[(c + 1) & 1], pf)
    }

    // ---- epilogue: softmax over N (bias already in acc) + direct store ----
    // C/D layout: col n = lane&31, row rr = (r&3) + 8*(r>>2) + 4*hf
#pragma unroll
    for (int ms = 0; ms < 2; ms++) {
#pragma unroll
        for (int r = 0; r < 16; r++) {
            float mx = acc[ms][0][r];
#pragma unroll
            for (int nt = 1; nt < 8; nt++) mx = fmaxf(mx, acc[ms][nt][r]);
#pragma unroll
            for (int off = 1; off < 32; off <<= 1) mx = fmaxf(mx, __shfl_xor(mx, off));
            if (l31 == r) red[wn][ms * 32 + (r & 3) + 8 * (r >> 2) + 4 * hf] = mx;
        }
    }
    __syncthreads();
    if (tid < 64) {
        float v = red[0][tid];
#pragma unroll
        for (int w = 1; w < 4; w++) v = fmaxf(v, red[w][tid]);
        redc[tid] = v;
    }
    __syncthreads();

#pragma unroll
    for (int ms = 0; ms < 2; ms++) {
#pragma unroll
        for (int r = 0; r < 16; r++) {
            const int rr = ms * 32 + (r & 3) + 8 * (r >> 2) + 4 * hf;
            const float rm = redc[rr];
            float s = 0.f;
#pragma unroll
            for (int nt = 0; nt < 8; nt++) {
                float e = __expf(acc[ms][nt][r] - rm);
                acc[ms][nt][r] = e;
                s += e;
            }
#pragma unroll
            for (int off = 1; off < 32; off <<= 1) s += __shfl_xor(s, off);
            if (l31 == r) red[wn][rr] = s;
        }
    }
    __syncthreads();
    if (tid < 64) {
        float v = 0.f;
#pragma unroll
        for (int w = 0; w < 4; w++) v += red[w][tid];
        redc[tid] = 1.0f / v;
    }
    __syncthreads();

#pragma unroll
    for (int ms = 0; ms < 2; ms++) {
        float invr[16];
#pragma unroll
        for (int r = 0; r < 16; r++)
            invr[r] = redc[ms * 32 + (r & 3) + 8 * (r >> 2) + 4 * hf];
#pragma unroll
        for (int nt = 0; nt < 8; nt++) {
            const int n = wn * 256 + nt * 32 + l31;
            float* op = out + ((size_t)b * Nd + n) * Ld + l0 + ms * 32 + hf * 4;
#pragma unroll
            for (int g = 0; g < 4; g++) {
                float4 v = make_float4(acc[ms][nt][g * 4 + 0] * invr[g * 4 + 0],
                                       acc[ms][nt][g * 4 + 1] * invr[g * 4 + 1],
                                       acc[ms][nt][g * 4 + 2] * invr[g * 4 + 2],
                                       acc[ms][nt][g * 4 + 3] * invr[g * 4 + 3]);
                *(float4*)(op + 8 * g) = v;
            }
        }
    }
}

// ---------------------------------------------------------------------------
// Workspace layout (4.3 MB):
//   bias f32 [1024]   4 KB @ 0x0
//   Bh   f16 [1M]     2 MB @ 0x10000
//   Bl   f16 [1M]     2 MB @ 0x210000
// ---------------------------------------------------------------------------
extern "C" void kernel_launch(void* const* d_in, const int* in_sizes, int n_in,
                              void* d_out, int out_size, void* d_ws, size_t ws_size,
                              hipStream_t stream) {
    (void)in_sizes; (void)n_in; (void)out_size; (void)ws_size;

    const float* F    = (const float*)d_in[0];   // (768, 512)
    const float* enc  = (const float*)d_in[1];   // (512, 32, 1024)
    const float* Wlin = (const float*)d_in[2];   // (512, 1024)
    const float* blin = (const float*)d_in[3];   // (512,)
    const float* Wfea = (const float*)d_in[4];   // (512, 1024)
    const float* bfea = (const float*)d_in[5];   // (512,)
    const float* V    = (const float*)d_in[6];   // (256, 512)
    float* out = (float*)d_out;                  // (32, 1024, 512)

    char* ws = (char*)d_ws;
    float*    bias = (float*)ws;                  // 4 KB
    _Float16* Bh   = (_Float16*)(ws + 0x10000);   // 2 MB
    _Float16* Bl   = (_Float16*)(ws + 0x210000);  // 2 MB

    build_wpack<<<dim3(8, 32), 256, 0, stream>>>(F, Wfea, V, Wlin, Bh, Bl);
    build_bias<<<dim3(1024), 64, 0, stream>>>(F, bfea, V, blin, bias);
    gemm_direct<<<dim3(256), 256, 0, stream>>>(enc, Bh, Bl, bias, out);
}

// Round 10
// 221.827 us; speedup vs baseline: 2.9916x; 2.9916x over previous
//
#include <hip/hip_runtime.h>
#include <hip/hip_bf16.h>
#include <math.h>

#define Hd   512
#define FPd  256
#define Ed   512
#define NFd  768
#define Ld   512
#define Bd   32
#define K2H  1024            // 2H
#define Nd   1024            // NF + FP
#define Md   (Ld * Bd)       // 16384

typedef _Float16 f16x8  __attribute__((ext_vector_type(8)));
typedef _Float16 f16x4  __attribute__((ext_vector_type(4)));
typedef float    f32x4  __attribute__((ext_vector_type(4)));
typedef float    f32x16 __attribute__((ext_vector_type(16)));

// ---------------------------------------------------------------------------
// Kernel 1: fused W_big build + fp16 hi/lo frag repack.
//   W_big[n][k] = sum_e F[n][e]*W_feat[e][k]   (n < NF)
//              =  sum_h v[n-NF][h]*W_lin[h][k] (n >= NF)
// Frag layout: fo = ((ntile*64 + k16)*64 + lane)*8,
//   n = ntile*32+(lane&31), k = k16*16+(lane>>5)*8+j.
// ---------------------------------------------------------------------------
__global__ __launch_bounds__(256)
void build_wpack(const float* __restrict__ F,
                 const float* __restrict__ Wf,
                 const float* __restrict__ V,
                 const float* __restrict__ Wl,
                 _Float16* __restrict__ Bh, _Float16* __restrict__ Bl) {
    __shared__ float fs[32][64];
    __shared__ float wtile[32][132];    // padded stride
    const int tid = threadIdx.x;
    const int kx  = blockIdx.x;
    const int ny  = blockIdx.y;
    const int n0  = ny * 32;
    const int kl  = tid & 127;          // local k
    const int k   = kx * 128 + kl;
    const int ty  = tid >> 7;

    const float* src;  const float* wsrc;
    if (n0 < NFd) { src = F + (size_t)n0 * Ed;          wsrc = Wf; }
    else          { src = V + (size_t)(n0 - NFd) * Hd;  wsrc = Wl; }

    float acc[16];
#pragma unroll
    for (int i = 0; i < 16; i++) acc[i] = 0.f;

    for (int e0 = 0; e0 < 512; e0 += 64) {
#pragma unroll
        for (int rep = 0; rep < 2; rep++) {
            int idx = rep * 256 + tid;
            int i   = idx >> 4;
            int kq  = idx & 15;
            float4 v4 = *(const float4*)(src + (size_t)i * 512 + e0 + kq * 4);
            *(float4*)(&fs[i][kq * 4]) = v4;
        }
        __syncthreads();
#pragma unroll 4
        for (int kk = 0; kk < 64; kk += 4) {
            float w0 = wsrc[(size_t)(e0 + kk + 0) * K2H + k];
            float w1 = wsrc[(size_t)(e0 + kk + 1) * K2H + k];
            float w2 = wsrc[(size_t)(e0 + kk + 2) * K2H + k];
            float w3 = wsrc[(size_t)(e0 + kk + 3) * K2H + k];
#pragma unroll
            for (int i = 0; i < 16; i++) {
                float4 f4 = *(const float4*)(&fs[ty * 16 + i][kk]);
                acc[i] += f4.x * w0 + f4.y * w1 + f4.z * w2 + f4.w * w3;
            }
        }
        __syncthreads();
    }
    // phase 2: stage to LDS, emit frags
#pragma unroll
    for (int i = 0; i < 16; i++) wtile[ty * 16 + i][kl] = acc[i];
    __syncthreads();
#pragma unroll
    for (int s = 0; s < 2; s++) {
        const int slot = s * 256 + tid;       // 0..511
        const int lane = slot & 63;
        const int ksl  = slot >> 6;           // 0..7
        const int nl   = lane & 31;
        const int kf   = ksl * 16 + (lane >> 5) * 8;
        float w[8];
        *(float4*)(w)     = *(const float4*)(&wtile[nl][kf]);
        *(float4*)(w + 4) = *(const float4*)(&wtile[nl][kf + 4]);
        f16x8 h, l;
#pragma unroll
        for (int j = 0; j < 8; j++) {
            _Float16 hh = (_Float16)w[j];
            h[j] = hh;
            l[j] = (_Float16)(w[j] - (float)hh);
        }
        const size_t fo = ((size_t)((ny * 8 + kx) * 8 + ksl) * 64 + lane) * 8;
        *(f16x8*)(Bh + fo) = h;
        *(f16x8*)(Bl + fo) = l;
    }
}

// ---------------------------------------------------------------------------
// Kernel 1b: bias_big[n]
// ---------------------------------------------------------------------------
__global__ __launch_bounds__(64)
void build_bias(const float* __restrict__ F, const float* __restrict__ bf,
                const float* __restrict__ V, const float* __restrict__ bl,
                float* __restrict__ bias) {
    const int n    = blockIdx.x;
    const int lane = threadIdx.x;
    const float* row; const float* bsrc;
    if (n < NFd) { row = F + (size_t)n * Ed;          bsrc = bf; }
    else         { row = V + (size_t)(n - NFd) * Hd;  bsrc = bl; }
    float a = 0.f;
#pragma unroll
    for (int rep = 0; rep < 8; rep++) {
        int e = rep * 64 + lane;
        a += row[e] * bsrc[e];
    }
#pragma unroll
    for (int off = 1; off < 64; off <<= 1) a += __shfl_xor(a, off);
    if (lane == 0) bias[n] = a;
}

// ---------------------------------------------------------------------------
// Kernel 2: MFMA GEMM (fp16x3 split) + fused softmax + direct transposed
// store. Grid 256 = (b, lc): 64 rows (fixed b, 64 l) x N=1024.
// 1024 thr = 16 WAVES -> 4 waves/SIMD (TLP hides B-load L2 latency).
// Wave wn owns cols wn*64 (2 nt of 32) x 64 rows (2 ms of 32):
// acc[2][2] = 64 AGPR; launch_bounds(1024) forces <=128 total regs.
// A: BK=64 chunks, f16 hi/lo LDS planes (converted once), dbuf, XOR-swz.
// B: direct global frag loads (L2-resident). Bias folded into acc init.
// ---------------------------------------------------------------------------
__global__ __launch_bounds__(1024)
void gemm_direct(const float* __restrict__ enc,
                 const _Float16* __restrict__ Bh,
                 const _Float16* __restrict__ Bl,
                 const float* __restrict__ bias,
                 float* __restrict__ out) {
    // per buf: hi plane 8KB @0, lo plane 8KB @8192 (row stride 128B)
    __shared__ char AsB[2][16384];
    __shared__ float red[16][64];
    __shared__ float redc[64];

    const int tid  = threadIdx.x;
    const int lane = tid & 63;
    const int wn   = tid >> 6;         // wave 0..15 -> 64-col block
    const int hf   = lane >> 5;
    const int l31  = lane & 31;
    const int b    = blockIdx.x >> 3;  // 0..31
    const int l0   = (blockIdx.x & 7) * 64;

    // bias folded into accumulator init
    float bv[2];
#pragma unroll
    for (int nt = 0; nt < 2; nt++) bv[nt] = bias[wn * 64 + nt * 32 + l31];
    f32x16 acc[2][2];
#pragma unroll
    for (int ms = 0; ms < 2; ms++)
#pragma unroll
        for (int nt = 0; nt < 2; nt++)
#pragma unroll
            for (int r = 0; r < 16; r++) acc[ms][nt][r] = bv[nt];

    // staging map: thread -> (row = tid>>4 in 0..63, 4 k at (tid&15)*4)
    const int srow = tid >> 4;
    const int skf  = (tid & 15) * 4;
    const float* gA = enc + ((size_t)(l0 + srow) * Bd + b) * K2H + skf;
    const uint32_t wswz = (uint32_t)((srow & 7) << 4);
    const uint32_t wb0  = (uint32_t)(srow * 128 + skf * 2);

    // read map: row = ms*32 + l31 -> row&7 == l31&7
    const uint32_t rswz = (uint32_t)((l31 & 7) << 4);

#define STAGE_CHUNK(dst, p)                                               \
    {                                                                     \
        char* base_ = (dst);                                              \
        f16x4 h_, l_;                                                     \
        _Pragma("unroll")                                                 \
        for (int j = 0; j < 4; j++) {                                     \
            float f_ = (p)[j];                                            \
            _Float16 hh_ = (_Float16)f_;                                  \
            h_[j] = hh_;                                                  \
            l_[j] = (_Float16)(f_ - (float)hh_);                          \
        }                                                                 \
        const uint32_t o_ = wb0 ^ wswz;                                   \
        *(f16x4*)(base_ + o_)        = h_;                                \
        *(f16x4*)(base_ + 8192 + o_) = l_;                                \
    }

    // prologue: stage chunk 0 into buf 0
    {
        f32x4 p = *(const f32x4*)gA;
        STAGE_CHUNK(AsB[0], p)
    }

    for (int c = 0; c < 16; ++c) {
        __syncthreads();               // buf[c&1] staged; buf[(c+1)&1] free
        f32x4 p;
        if (c < 15) p = *(const f32x4*)(gA + (c + 1) * 64);  // issue early
        const char* hbase = AsB[c & 1];
        const char* lbase = AsB[c & 1] + 8192;
#pragma unroll
        for (int kk = 0; kk < 4; ++kk) {
            const uint32_t ko = (uint32_t)(kk * 32 + hf * 16);
            f16x8 a_h[2], a_l[2];
#pragma unroll
            for (int ms = 0; ms < 2; ms++) {
                const uint32_t ad = (uint32_t)((ms * 32 + l31) * 128 + ko) ^ rswz;
                a_h[ms] = *(const f16x8*)(hbase + ad);
                a_l[ms] = *(const f16x8*)(lbase + ad);
            }
#pragma unroll
            for (int nt = 0; nt < 2; ++nt) {
                const size_t fo = ((size_t)((wn * 2 + nt) * 64 + c * 4 + kk) * 64 + lane) * 8;
                f16x8 b_h = *(const f16x8*)(Bh + fo);
                f16x8 b_l = *(const f16x8*)(Bl + fo);
                acc[0][nt] = __builtin_amdgcn_mfma_f32_32x32x16_f16(a_h[0], b_h, acc[0][nt], 0, 0, 0);
                acc[1][nt] = __builtin_amdgcn_mfma_f32_32x32x16_f16(a_h[1], b_h, acc[1][nt], 0, 0, 0);
                acc[0][nt] = __builtin_amdgcn_mfma_f32_32x32x16_f16(a_l[0], b_h, acc[0][nt], 0, 0, 0);
                acc[1][nt] = __builtin_amdgcn_mfma_f32_32x32x16_f16(a_l[1], b_h, acc[1][nt], 0, 0, 0);
                acc[0][nt] = __builtin_amdgcn_mfma_f32_32x32x16_f16(a_h[0], b_l, acc[0][nt], 0, 0, 0);
                acc[1][nt] = __builtin_amdgcn_mfma_f32_32x32x16_f16(a_h[1], b_l, acc[1][nt], 0, 0, 0);
            }
        }
        if (c < 15) STAGE_CHUNK(AsB[(c + 1) & 1], p)
    }

    // ---- epilogue: softmax over N (bias already in acc) + direct store ----
    // C/D layout: col n = lane&31, row rr = (r&3) + 8*(r>>2) + 4*hf
#pragma unroll
    for (int ms = 0; ms < 2; ms++) {
#pragma unroll
        for (int r = 0; r < 16; r++) {
            float mx = fmaxf(acc[ms][0][r], acc[ms][1][r]);
#pragma unroll
            for (int off = 1; off < 32; off <<= 1) mx = fmaxf(mx, __shfl_xor(mx, off));
            if (l31 == r) red[wn][ms * 32 + (r & 3) + 8 * (r >> 2) + 4 * hf] = mx;
        }
    }
    __syncthreads();
    if (tid < 64) {
        float v = red[0][tid];
#pragma unroll
        for (int w = 1; w < 16; w++) v = fmaxf(v, red[w][tid]);
        redc[tid] = v;
    }
    __syncthreads();

#pragma unroll
    for (int ms = 0; ms < 2; ms++) {
#pragma unroll
        for (int r = 0; r < 16; r++) {
            const int rr = ms * 32 + (r & 3) + 8 * (r >> 2) + 4 * hf;
            const float rm = redc[rr];
            float s = 0.f;
#pragma unroll
            for (int nt = 0; nt < 2; nt++) {
                float e = __expf(acc[ms][nt][r] - rm);
                acc[ms][nt][r] = e;
                s += e;
            }
#pragma unroll
            for (int off = 1; off < 32; off <<= 1) s += __shfl_xor(s, off);
            if (l31 == r) red[wn][rr] = s;
        }
    }
    __syncthreads();
    if (tid < 64) {
        float v = 0.f;
#pragma unroll
        for (int w = 0; w < 16; w++) v += red[w][tid];
        redc[tid] = 1.0f / v;
    }
    __syncthreads();

#pragma unroll
    for (int ms = 0; ms < 2; ms++) {
        float invr[16];
#pragma unroll
        for (int r = 0; r < 16; r++)
            invr[r] = redc[ms * 32 + (r & 3) + 8 * (r >> 2) + 4 * hf];
#pragma unroll
        for (int nt = 0; nt < 2; nt++) {
            const int n = wn * 64 + nt * 32 + l31;
            float* op = out + ((size_t)b * Nd + n) * Ld + l0 + ms * 32 + hf * 4;
#pragma unroll
            for (int g = 0; g < 4; g++) {
                float4 v = make_float4(acc[ms][nt][g * 4 + 0] * invr[g * 4 + 0],
                                       acc[ms][nt][g * 4 + 1] * invr[g * 4 + 1],
                                       acc[ms][nt][g * 4 + 2] * invr[g * 4 + 2],
                                       acc[ms][nt][g * 4 + 3] * invr[g * 4 + 3]);
                *(float4*)(op + 8 * g) = v;
            }
        }
    }
}

// ---------------------------------------------------------------------------
// Workspace layout (4.3 MB):
//   bias f32 [1024]   4 KB @ 0x0
//   Bh   f16 [1M]     2 MB @ 0x10000
//   Bl   f16 [1M]     2 MB @ 0x210000
// ---------------------------------------------------------------------------
extern "C" void kernel_launch(void* const* d_in, const int* in_sizes, int n_in,
                              void* d_out, int out_size, void* d_ws, size_t ws_size,
                              hipStream_t stream) {
    (void)in_sizes; (void)n_in; (void)out_size; (void)ws_size;

    const float* F    = (const float*)d_in[0];   // (768, 512)
    const float* enc  = (const float*)d_in[1];   // (512, 32, 1024)
    const float* Wlin = (const float*)d_in[2];   // (512, 1024)
    const float* blin = (const float*)d_in[3];   // (512,)
    const float* Wfea = (const float*)d_in[4];   // (512, 1024)
    const float* bfea = (const float*)d_in[5];   // (512,)
    const float* V    = (const float*)d_in[6];   // (256, 512)
    float* out = (float*)d_out;                  // (32, 1024, 512)

    char* ws = (char*)d_ws;
    float*    bias = (float*)ws;                  // 4 KB
    _Float16* Bh   = (_Float16*)(ws + 0x10000);   // 2 MB
    _Float16* Bl   = (_Float16*)(ws + 0x210000);  // 2 MB

    build_wpack<<<dim3(8, 32), 256, 0, stream>>>(F, Wfea, V, Wlin, Bh, Bl);
    build_bias<<<dim3(1024), 64, 0, stream>>>(F, bfea, V, blin, bias);
    gemm_direct<<<dim3(256), 1024, 0, stream>>>(enc, Bh, Bl, bias, out);
}